// Round 3
// baseline (420.766 us; speedup 1.0000x reference)
//
#include <hip/hip_runtime.h>
#include <hip/hip_bf16.h>

// PointerNet: out[b][k] = sum_c C_k[b,c] * sigmoid(WP[b,c]+WC_k[b,c]+Gb[c]) * (WPo[b,c]+Ob[c])
//   GEMM A: WPcat = P @ [GateWeight_P | OutWeight]  (M=8192,N=2048,K=1024)
//   GEMM B: WC_k = C_k @ GateWeight_C, fused with the sigmoid/dot epilogue:
//           each block reduces its own (row-tile x col-tile) partition and
//           atomicAdds partial sums into out. WC is never materialized.
// R3: 3 launches: prep (cast5+transpose3+zero-out) -> gemmA -> gemmB_fused.

#define B_  8192
#define PD_ 1024
#define CD_ 1024

typedef unsigned short ushort_t;
typedef __attribute__((ext_vector_type(8))) short    short8;
typedef __attribute__((ext_vector_type(8))) unsigned short ushort8;
typedef __attribute__((ext_vector_type(4))) float    floatx4;

__device__ __forceinline__ float bf2f(unsigned short u) {
    return __uint_as_float(((unsigned)u) << 16);
}
__device__ __forceinline__ unsigned short f2bf(float f) {
    unsigned u = __float_as_uint(f);
    unsigned r = u + 0x7FFFu + ((u >> 16) & 1u);   // RNE
    return (unsigned short)(r >> 16);
}

// ---------------- prep: cast P,C1..C4 -> bf16; transpose 3 weights; zero out ----------------
// blocks [0,40960): cast (5 segs x 8192) ; [40960,44032): transpose (3 x 1024) ;
// [44032,44064): zero out (32768 floats).
__global__ __launch_bounds__(256) void prep_kernel(const float* __restrict__ P,
                                                   const float* __restrict__ C1,
                                                   const float* __restrict__ C2,
                                                   const float* __restrict__ C3,
                                                   const float* __restrict__ C4,
                                                   const float* __restrict__ GWP,
                                                   const float* __restrict__ OW,
                                                   const float* __restrict__ GWC,
                                                   ushort_t* __restrict__ Pb,
                                                   ushort_t* __restrict__ Call,
                                                   ushort_t* __restrict__ Wcat,
                                                   ushort_t* __restrict__ GWCt,
                                                   float* __restrict__ out) {
    const int bid = blockIdx.x;
    const int tid = threadIdx.x;
    if (bid < 40960) {
        const int seg = bid >> 13;
        const int i   = (bid & 8191) * 256 + tid;
        const float* src;
        ushort_t* dst;
        switch (seg) {
            case 0: src = P;  dst = Pb; break;
            case 1: src = C1; dst = Call; break;
            case 2: src = C2; dst = Call + (size_t)1 * B_ * CD_; break;
            case 3: src = C3; dst = Call + (size_t)2 * B_ * CD_; break;
            default: src = C4; dst = Call + (size_t)3 * B_ * CD_; break;
        }
        float4 v = ((const float4*)src)[i];
        ushort4 o;
        o.x = f2bf(v.x); o.y = f2bf(v.y); o.z = f2bf(v.z); o.w = f2bf(v.w);
        ((ushort4*)dst)[i] = o;
    } else if (bid < 44032) {
        __shared__ float tile[32][33];
        const int tb  = bid - 40960;
        const int seg = tb >> 10;
        const int t32 = tb & 1023;
        const float* src;
        ushort_t* dst;
        switch (seg) {
            case 0: src = GWP; dst = Wcat; break;
            case 1: src = OW;  dst = Wcat + 1024 * 1024; break;
            default: src = GWC; dst = GWCt; break;
        }
        const int c0 = (t32 & 31) * 32, r0 = (t32 >> 5) * 32;
        const int x = tid & 31, y = tid >> 5;           // (32,8)
        for (int i = y; i < 32; i += 8)
            tile[i][x] = src[(size_t)(r0 + i) * 1024 + c0 + x];
        __syncthreads();
        for (int i = y; i < 32; i += 8)
            dst[(size_t)(c0 + i) * 1024 + r0 + x] = f2bf(tile[x][i]);
    } else {
        const int i = (bid - 44032) * 256 + tid;        // 8192 float4s
        ((float4*)out)[i] = float4{0.f, 0.f, 0.f, 0.f};
    }
}

// ---------------- shared GEMM pieces ----------------
__device__ __forceinline__ void gl_lds16(const void* g, void* l) {
    __builtin_amdgcn_global_load_lds((const __attribute__((address_space(1))) void*)g,
                                     (__attribute__((address_space(3))) void*)l, 16, 0, 0);
}

// ---------------- GEMM A: WPcat = Pb @ Wcat^T, writes bf16 C ----------------
__global__ __launch_bounds__(256) void gemmA(const ushort_t* __restrict__ A,
                                             const ushort_t* __restrict__ Bt,
                                             ushort_t* __restrict__ C) {
    __shared__ ushort_t lA[128 * 32];
    __shared__ ushort_t lB[128 * 32];
    const int K = 1024, N = 2048;
    const int tileN = (blockIdx.x & 15) * 128, tileM = (blockIdx.x >> 4) * 128;

    const int t = threadIdx.x;
    const int wave = t >> 6, lane = t & 63;
    const int quad = lane >> 4, l16 = lane & 15;
    const int wm = wave >> 1, wn = wave & 1;

    const int ch0  = wave * 2;
    const int srow = lane >> 2;
    const int sc   = ((lane & 3) ^ ((lane >> 4) & 3)) * 8;
    const int lo0  = ch0 * 512 + lane * 8;

    const ushort_t* Ag0 = A  + (size_t)(tileM + ch0 * 16 + srow)      * K + sc;
    const ushort_t* Ag1 = A  + (size_t)(tileM + ch0 * 16 + srow + 16) * K + sc;
    const ushort_t* Bg0 = Bt + (size_t)(tileN + ch0 * 16 + srow)      * K + sc;
    const ushort_t* Bg1 = Bt + (size_t)(tileN + ch0 * 16 + srow + 16) * K + sc;

    const int fro = (l16 * 4 + (quad ^ (l16 >> 2))) * 8;

    floatx4 acc[4][4];
#pragma unroll
    for (int i = 0; i < 4; i++)
#pragma unroll
        for (int j = 0; j < 4; j++) acc[i][j] = (floatx4)0.f;

    for (int k0 = 0; k0 < K; k0 += 32) {
        gl_lds16(Ag0 + k0, &lA[lo0]);
        gl_lds16(Ag1 + k0, &lA[lo0 + 512]);
        gl_lds16(Bg0 + k0, &lB[lo0]);
        gl_lds16(Bg1 + k0, &lB[lo0 + 512]);
        __syncthreads();
        short8 af[4], bfr[4];
#pragma unroll
        for (int mi = 0; mi < 4; mi++)
            af[mi] = *(const short8*)&lA[(wm * 4 + mi) * 512 + fro];
#pragma unroll
        for (int ni = 0; ni < 4; ni++)
            bfr[ni] = *(const short8*)&lB[(wn * 4 + ni) * 512 + fro];
#pragma unroll
        for (int mi = 0; mi < 4; mi++)
#pragma unroll
            for (int ni = 0; ni < 4; ni++)
                acc[mi][ni] = __builtin_amdgcn_mfma_f32_16x16x32_bf16(
                    af[mi], bfr[ni], acc[mi][ni], 0, 0, 0);
        __syncthreads();
    }
#pragma unroll
    for (int mi = 0; mi < 4; mi++)
#pragma unroll
        for (int ni = 0; ni < 4; ni++)
#pragma unroll
            for (int r = 0; r < 4; r++) {
                int row = tileM + wm * 64 + mi * 16 + quad * 4 + r;
                int col = tileN + wn * 64 + ni * 16 + l16;
                C[(size_t)row * N + col] = f2bf(acc[mi][ni][r]);
            }
}

// ---------------- GEMM B + fused epilogue ----------------
// Computes WC tile (128 rows of [4*B] space x 128 of 1024 cols), then reduces
// partial = sum_c Ck * sigmoid(WP+WC+Gb) * (WPo+Ob) over its col slice and
// atomicAdds into out[b][k]. Needs WPcat from gemmA.
__global__ __launch_bounds__(256) void gemmB_fused(const ushort_t* __restrict__ Call,
                                                   const ushort_t* __restrict__ GWCt,
                                                   const ushort_t* __restrict__ WPcat,
                                                   const float* __restrict__ Gb,
                                                   const float* __restrict__ Ob,
                                                   float* __restrict__ out) {
    // epilogue LDS: 128 x 136 bf16 = 34816 B; staging reuses the first 16 KB
    __shared__ ushort_t smem[128 * 136];
    ushort_t* lA = smem;
    ushort_t* lB = smem + 4096;
    const int K = 1024;
    const int tileN = (blockIdx.x & 7) * 128, tileM = (blockIdx.x >> 3) * 128;

    const int t = threadIdx.x;
    const int wave = t >> 6, lane = t & 63;
    const int quad = lane >> 4, l16 = lane & 15;
    const int wm = wave >> 1, wn = wave & 1;

    const int ch0  = wave * 2;
    const int srow = lane >> 2;
    const int sc   = ((lane & 3) ^ ((lane >> 4) & 3)) * 8;
    const int lo0  = ch0 * 512 + lane * 8;

    const ushort_t* Ag0 = Call + (size_t)(tileM + ch0 * 16 + srow)      * K + sc;
    const ushort_t* Ag1 = Call + (size_t)(tileM + ch0 * 16 + srow + 16) * K + sc;
    const ushort_t* Bg0 = GWCt + (size_t)(tileN + ch0 * 16 + srow)      * K + sc;
    const ushort_t* Bg1 = GWCt + (size_t)(tileN + ch0 * 16 + srow + 16) * K + sc;

    const int fro = (l16 * 4 + (quad ^ (l16 >> 2))) * 8;

    floatx4 acc[4][4];
#pragma unroll
    for (int i = 0; i < 4; i++)
#pragma unroll
        for (int j = 0; j < 4; j++) acc[i][j] = (floatx4)0.f;

    for (int k0 = 0; k0 < K; k0 += 32) {
        gl_lds16(Ag0 + k0, &lA[lo0]);
        gl_lds16(Ag1 + k0, &lA[lo0 + 512]);
        gl_lds16(Bg0 + k0, &lB[lo0]);
        gl_lds16(Bg1 + k0, &lB[lo0 + 512]);
        __syncthreads();
        short8 af[4], bfr[4];
#pragma unroll
        for (int mi = 0; mi < 4; mi++)
            af[mi] = *(const short8*)&lA[(wm * 4 + mi) * 512 + fro];
#pragma unroll
        for (int ni = 0; ni < 4; ni++)
            bfr[ni] = *(const short8*)&lB[(wn * 4 + ni) * 512 + fro];
#pragma unroll
        for (int mi = 0; mi < 4; mi++)
#pragma unroll
            for (int ni = 0; ni < 4; ni++)
                acc[mi][ni] = __builtin_amdgcn_mfma_f32_16x16x32_bf16(
                    af[mi], bfr[ni], acc[mi][ni], 0, 0, 0);
        __syncthreads();
    }

    // ---- epilogue: acc -> LDS (bf16, row stride 136 = 272B, 16B-aligned) ----
#pragma unroll
    for (int mi = 0; mi < 4; mi++)
#pragma unroll
        for (int ni = 0; ni < 4; ni++)
#pragma unroll
            for (int r = 0; r < 4; r++) {
                int rl = wm * 64 + mi * 16 + quad * 4 + r;
                int cl = wn * 64 + ni * 16 + l16;
                smem[rl * 136 + cl] = f2bf(acc[mi][ni][r]);
            }
    __syncthreads();

    // thread t: row = t>>1, col-half = (t&1)*64
    const int rl   = t >> 1;
    const int grow = tileM + rl;                 // = k*8192 + b
    const int kbr  = grow >> 13;
    const int b    = grow & 8191;
    const int ch   = (t & 1) * 64;

    float s = 0.f;
#pragma unroll
    for (int j = 0; j < 8; j++) {
        const int cl   = ch + j * 8;
        const int gcol = tileN + cl;
        ushort8 wc8  = *(const ushort8*)&smem[rl * 136 + cl];
        ushort8 wp8  = *(const ushort8*)&WPcat[(size_t)b * 2048 + gcol];
        ushort8 wpo8 = *(const ushort8*)&WPcat[(size_t)b * 2048 + 1024 + gcol];
        ushort8 ck8  = *(const ushort8*)&Call[(size_t)grow * 1024 + gcol];
        floatx4 g0 = *(const floatx4*)&Gb[gcol];
        floatx4 g1 = *(const floatx4*)&Gb[gcol + 4];
        floatx4 o0 = *(const floatx4*)&Ob[gcol];
        floatx4 o1 = *(const floatx4*)&Ob[gcol + 4];
        float gb[8], ob[8];
#pragma unroll
        for (int q = 0; q < 4; q++) { gb[q] = g0[q]; gb[4 + q] = g1[q]; ob[q] = o0[q]; ob[4 + q] = o1[q]; }
#pragma unroll
        for (int q = 0; q < 8; q++) {
            float x = bf2f(wp8[q]) + bf2f(wc8[q]) + gb[q];
            float g = 1.f / (1.f + __expf(-x));
            s += bf2f(ck8[q]) * g * (bf2f(wpo8[q]) + ob[q]);
        }
    }
    s += __shfl_xor(s, 1);                        // combine the two col-halves
    if ((t & 1) == 0)
        atomicAdd(&out[(size_t)b * 4 + kbr], s);
}

extern "C" void kernel_launch(void* const* d_in, const int* in_sizes, int n_in,
                              void* d_out, int out_size, void* d_ws, size_t ws_size,
                              hipStream_t stream) {
    (void)in_sizes; (void)n_in; (void)out_size; (void)ws_size;
    const float* P   = (const float*)d_in[0];
    const float* C1  = (const float*)d_in[1];
    const float* C2  = (const float*)d_in[2];
    const float* C3  = (const float*)d_in[3];
    const float* C4  = (const float*)d_in[4];
    const float* GWP = (const float*)d_in[5];
    const float* GWC = (const float*)d_in[6];
    const float* Gb  = (const float*)d_in[7];
    const float* OW  = (const float*)d_in[8];
    const float* Ob  = (const float*)d_in[9];
    float* out = (float*)d_out;

    // workspace (bf16): Pb 16MiB | Call 64MiB | Wcat 4MiB | GWCt 2MiB | WPcat 32MiB
    char* ws = (char*)d_ws;
    ushort_t* Pb    = (ushort_t*)(ws);
    ushort_t* Call  = (ushort_t*)(ws + (16u << 20));
    ushort_t* Wcat  = (ushort_t*)(ws + (80u << 20));
    ushort_t* GWCt  = (ushort_t*)(ws + (84u << 20));
    ushort_t* WPcat = (ushort_t*)(ws + (86u << 20));

    prep_kernel<<<44064, 256, 0, stream>>>(P, C1, C2, C3, C4, GWP, OW, GWC,
                                           Pb, Call, Wcat, GWCt, out);
    gemmA<<<1024, 256, 0, stream>>>(Pb, Wcat, WPcat);
    gemmB_fused<<<2048, 256, 0, stream>>>(Call, GWCt, WPcat, Gb, Ob, out);
}

// Round 4
// 398.159 us; speedup vs baseline: 1.0568x; 1.0568x over previous
//
#include <hip/hip_runtime.h>
#include <hip/hip_bf16.h>

// PointerNet: out[b][k] = sum_c C_k[b,c] * sigmoid(WP[b,c]+WC_k[b,c]+Gb[c]) * (WPo[b,c]+Ob[c])
//   GEMM A: WPcat = P @ [GateWeight_P | OutWeight]  (M=8192,N=2048,K=1024)
//   GEMM B: WC_k = C_k @ GateWeight_C fused with sigmoid/dot epilogue (atomicAdd out).
// R4: 128x256 tiles (512 thr, 8 waves 2x4, per-wave 64x64 acc[4][4] ~80 VGPR),
//     halving raw A-staging traffic; XCD swizzle puts all col-tiles of a row slab
//     on one XCD so A-tile reuse is served by that XCD's 4MB L2 (R3 showed zero
//     cross-XCD absorption: FETCH 581MB = raw). Epilogue in two 128-col halves
//     (LDS 34KB -> 2 blocks/CU).

#define B_  8192
#define PD_ 1024
#define CD_ 1024

typedef unsigned short ushort_t;
typedef __attribute__((ext_vector_type(8))) short    short8;
typedef __attribute__((ext_vector_type(8))) unsigned short ushort8;
typedef __attribute__((ext_vector_type(4))) float    floatx4;

__device__ __forceinline__ float bf2f(unsigned short u) {
    return __uint_as_float(((unsigned)u) << 16);
}
__device__ __forceinline__ unsigned short f2bf(float f) {
    unsigned u = __float_as_uint(f);
    unsigned r = u + 0x7FFFu + ((u >> 16) & 1u);   // RNE
    return (unsigned short)(r >> 16);
}

// ---------------- prep: cast P,C1..C4 -> bf16; transpose 3 weights; zero out ----------------
__global__ __launch_bounds__(256) void prep_kernel(const float* __restrict__ P,
                                                   const float* __restrict__ C1,
                                                   const float* __restrict__ C2,
                                                   const float* __restrict__ C3,
                                                   const float* __restrict__ C4,
                                                   const float* __restrict__ GWP,
                                                   const float* __restrict__ OW,
                                                   const float* __restrict__ GWC,
                                                   ushort_t* __restrict__ Pb,
                                                   ushort_t* __restrict__ Call,
                                                   ushort_t* __restrict__ Wcat,
                                                   ushort_t* __restrict__ GWCt,
                                                   float* __restrict__ out) {
    const int bid = blockIdx.x;
    const int tid = threadIdx.x;
    if (bid < 40960) {
        const int seg = bid >> 13;
        const int i   = (bid & 8191) * 256 + tid;
        const float* src;
        ushort_t* dst;
        switch (seg) {
            case 0: src = P;  dst = Pb; break;
            case 1: src = C1; dst = Call; break;
            case 2: src = C2; dst = Call + (size_t)1 * B_ * CD_; break;
            case 3: src = C3; dst = Call + (size_t)2 * B_ * CD_; break;
            default: src = C4; dst = Call + (size_t)3 * B_ * CD_; break;
        }
        float4 v = ((const float4*)src)[i];
        ushort4 o;
        o.x = f2bf(v.x); o.y = f2bf(v.y); o.z = f2bf(v.z); o.w = f2bf(v.w);
        ((ushort4*)dst)[i] = o;
    } else if (bid < 44032) {
        __shared__ float tile[32][33];
        const int tb  = bid - 40960;
        const int seg = tb >> 10;
        const int t32 = tb & 1023;
        const float* src;
        ushort_t* dst;
        switch (seg) {
            case 0: src = GWP; dst = Wcat; break;
            case 1: src = OW;  dst = Wcat + 1024 * 1024; break;
            default: src = GWC; dst = GWCt; break;
        }
        const int c0 = (t32 & 31) * 32, r0 = (t32 >> 5) * 32;
        const int x = tid & 31, y = tid >> 5;
        for (int i = y; i < 32; i += 8)
            tile[i][x] = src[(size_t)(r0 + i) * 1024 + c0 + x];
        __syncthreads();
        for (int i = y; i < 32; i += 8)
            dst[(size_t)(c0 + i) * 1024 + r0 + x] = f2bf(tile[x][i]);
    } else {
        const int i = (bid - 44032) * 256 + tid;
        ((float4*)out)[i] = float4{0.f, 0.f, 0.f, 0.f};
    }
}

__device__ __forceinline__ void gl_lds16(const void* g, void* l) {
    __builtin_amdgcn_global_load_lds((const __attribute__((address_space(1))) void*)g,
                                     (__attribute__((address_space(3))) void*)l, 16, 0, 0);
}

// ---------------- GEMM A: WPcat = Pb @ Wcat^T  (128x256 tile, 512 thr) ----------------
// grid 512: xcd=bid&7, q=bid>>3; slab=(q>>3)*8+xcd (64 slabs), colt=q&7 (8 cols).
__global__ __launch_bounds__(512, 4) void gemmA(const ushort_t* __restrict__ A,
                                                const ushort_t* __restrict__ Bt,
                                                ushort_t* __restrict__ C) {
    __shared__ ushort_t smem[12288];      // lA 4096 + lB 8192 elems = 24 KB
    ushort_t* lA = smem;
    ushort_t* lB = smem + 4096;
    const int K = 1024, N = 2048;
    const int xcd = blockIdx.x & 7, q = blockIdx.x >> 3;
    const int tileM = ((q >> 3) * 8 + xcd) * 128;
    const int tileN = (q & 7) * 256;

    const int t = threadIdx.x;
    const int wave = t >> 6, lane = t & 63;
    const int quad = lane >> 4, l16 = lane & 15;
    const int wm = wave >> 2, wn = wave & 3;

    const int srow = lane >> 2;
    const int sc   = ((lane & 3) ^ ((lane >> 4) & 3)) * 8;
    const ushort_t* Ag  = A  + (size_t)(tileM + wave * 16 + srow) * K + sc;
    const ushort_t* Bg0 = Bt + (size_t)(tileN + wave * 32 + srow) * K + sc;
    const ushort_t* Bg1 = Bg0 + (size_t)16 * K;
    const int loA = wave * 512 + lane * 8;
    const int loB = wave * 1024 + lane * 8;
    const int fro = (l16 * 4 + (quad ^ (l16 >> 2))) * 8;

    floatx4 acc[4][4];
#pragma unroll
    for (int i = 0; i < 4; i++)
#pragma unroll
        for (int j = 0; j < 4; j++) acc[i][j] = (floatx4)0.f;

    for (int k0 = 0; k0 < K; k0 += 32) {
        gl_lds16(Ag + k0,  &lA[loA]);
        gl_lds16(Bg0 + k0, &lB[loB]);
        gl_lds16(Bg1 + k0, &lB[loB + 512]);
        __syncthreads();
        short8 af[4], bfr[4];
#pragma unroll
        for (int mi = 0; mi < 4; mi++)
            af[mi] = *(const short8*)&lA[(wm * 4 + mi) * 512 + fro];
#pragma unroll
        for (int ni = 0; ni < 4; ni++)
            bfr[ni] = *(const short8*)&lB[(wn * 4 + ni) * 512 + fro];
#pragma unroll
        for (int mi = 0; mi < 4; mi++)
#pragma unroll
            for (int ni = 0; ni < 4; ni++)
                acc[mi][ni] = __builtin_amdgcn_mfma_f32_16x16x32_bf16(
                    af[mi], bfr[ni], acc[mi][ni], 0, 0, 0);
        __syncthreads();
    }
#pragma unroll
    for (int mi = 0; mi < 4; mi++)
#pragma unroll
        for (int ni = 0; ni < 4; ni++)
#pragma unroll
            for (int r = 0; r < 4; r++) {
                int row = tileM + wm * 64 + mi * 16 + quad * 4 + r;
                int col = tileN + wn * 64 + ni * 16 + l16;
                C[(size_t)row * N + col] = f2bf(acc[mi][ni][r]);
            }
}

// ---------------- GEMM B + fused epilogue (128x256 tile, 512 thr) ----------------
// grid 1024: xcd=bid&7, q=bid>>3; slab=(q>>2)*8+xcd (256 slabs), colt=q&3 (4 cols).
__global__ __launch_bounds__(512, 4) void gemmB_fused(const ushort_t* __restrict__ Call,
                                                      const ushort_t* __restrict__ GWCt,
                                                      const ushort_t* __restrict__ WPcat,
                                                      const float* __restrict__ Gb,
                                                      const float* __restrict__ Ob,
                                                      float* __restrict__ out) {
    __shared__ ushort_t smem[128 * 136];   // 34816 B; staging uses first 24 KB
    ushort_t* lA = smem;
    ushort_t* lB = smem + 4096;
    const int K = 1024;
    const int xcd = blockIdx.x & 7, q = blockIdx.x >> 3;
    const int tileM = ((q >> 2) * 8 + xcd) * 128;
    const int tileN = (q & 3) * 256;

    const int t = threadIdx.x;
    const int wave = t >> 6, lane = t & 63;
    const int quad = lane >> 4, l16 = lane & 15;
    const int wm = wave >> 2, wn = wave & 3;

    const int srow = lane >> 2;
    const int sc   = ((lane & 3) ^ ((lane >> 4) & 3)) * 8;
    const ushort_t* Ag  = Call + (size_t)(tileM + wave * 16 + srow) * K + sc;
    const ushort_t* Bg0 = GWCt + (size_t)(tileN + wave * 32 + srow) * K + sc;
    const ushort_t* Bg1 = Bg0 + (size_t)16 * K;
    const int loA = wave * 512 + lane * 8;
    const int loB = wave * 1024 + lane * 8;
    const int fro = (l16 * 4 + (quad ^ (l16 >> 2))) * 8;

    floatx4 acc[4][4];
#pragma unroll
    for (int i = 0; i < 4; i++)
#pragma unroll
        for (int j = 0; j < 4; j++) acc[i][j] = (floatx4)0.f;

    for (int k0 = 0; k0 < K; k0 += 32) {
        gl_lds16(Ag + k0,  &lA[loA]);
        gl_lds16(Bg0 + k0, &lB[loB]);
        gl_lds16(Bg1 + k0, &lB[loB + 512]);
        __syncthreads();
        short8 af[4], bfr[4];
#pragma unroll
        for (int mi = 0; mi < 4; mi++)
            af[mi] = *(const short8*)&lA[(wm * 4 + mi) * 512 + fro];
#pragma unroll
        for (int ni = 0; ni < 4; ni++)
            bfr[ni] = *(const short8*)&lB[(wn * 4 + ni) * 512 + fro];
#pragma unroll
        for (int mi = 0; mi < 4; mi++)
#pragma unroll
            for (int ni = 0; ni < 4; ni++)
                acc[mi][ni] = __builtin_amdgcn_mfma_f32_16x16x32_bf16(
                    af[mi], bfr[ni], acc[mi][ni], 0, 0, 0);
        __syncthreads();
    }

    // ---- fused epilogue, two 128-col halves ----
    const int rl   = t >> 2;                 // 0..127
    const int cq   = (t & 3) * 32;           // col quarter within the 128-half
    const int grow = tileM + rl;             // = k*8192 + b
    const int kbr  = grow >> 13;
    const int b    = grow & 8191;
    float s = 0.f;

#pragma unroll
    for (int h = 0; h < 2; h++) {
        __syncthreads();
        if ((wn >> 1) == h) {                // waves holding cols h*128..h*128+127
#pragma unroll
            for (int mi = 0; mi < 4; mi++)
#pragma unroll
                for (int ni = 0; ni < 4; ni++)
#pragma unroll
                    for (int r = 0; r < 4; r++) {
                        int rlw = wm * 64 + mi * 16 + quad * 4 + r;
                        int clw = (wn & 1) * 64 + ni * 16 + l16;
                        smem[rlw * 136 + clw] = f2bf(acc[mi][ni][r]);
                    }
        }
        __syncthreads();
#pragma unroll
        for (int j = 0; j < 4; j++) {
            const int cl   = cq + j * 8;
            const int gcol = tileN + h * 128 + cl;
            ushort8 wc8  = *(const ushort8*)&smem[rl * 136 + cl];
            ushort8 wp8  = *(const ushort8*)&WPcat[(size_t)b * 2048 + gcol];
            ushort8 wpo8 = *(const ushort8*)&WPcat[(size_t)b * 2048 + 1024 + gcol];
            ushort8 ck8  = *(const ushort8*)&Call[(size_t)grow * 1024 + gcol];
            floatx4 g0 = *(const floatx4*)&Gb[gcol];
            floatx4 g1 = *(const floatx4*)&Gb[gcol + 4];
            floatx4 o0 = *(const floatx4*)&Ob[gcol];
            floatx4 o1 = *(const floatx4*)&Ob[gcol + 4];
            float gb[8], ob[8];
#pragma unroll
            for (int p = 0; p < 4; p++) { gb[p] = g0[p]; gb[4 + p] = g1[p]; ob[p] = o0[p]; ob[4 + p] = o1[p]; }
#pragma unroll
            for (int p = 0; p < 8; p++) {
                float x = bf2f(wp8[p]) + bf2f(wc8[p]) + gb[p];
                float g = 1.f / (1.f + __expf(-x));
                s += bf2f(ck8[p]) * g * (bf2f(wpo8[p]) + ob[p]);
            }
        }
    }
    s += __shfl_xor(s, 1);
    s += __shfl_xor(s, 2);
    if ((t & 3) == 0)
        atomicAdd(&out[(size_t)b * 4 + kbr], s);
}

extern "C" void kernel_launch(void* const* d_in, const int* in_sizes, int n_in,
                              void* d_out, int out_size, void* d_ws, size_t ws_size,
                              hipStream_t stream) {
    (void)in_sizes; (void)n_in; (void)out_size; (void)ws_size;
    const float* P   = (const float*)d_in[0];
    const float* C1  = (const float*)d_in[1];
    const float* C2  = (const float*)d_in[2];
    const float* C3  = (const float*)d_in[3];
    const float* C4  = (const float*)d_in[4];
    const float* GWP = (const float*)d_in[5];
    const float* GWC = (const float*)d_in[6];
    const float* Gb  = (const float*)d_in[7];
    const float* OW  = (const float*)d_in[8];
    const float* Ob  = (const float*)d_in[9];
    float* out = (float*)d_out;

    // workspace (bf16): Pb 16MiB | Call 64MiB | Wcat 4MiB | GWCt 2MiB | WPcat 32MiB
    char* ws = (char*)d_ws;
    ushort_t* Pb    = (ushort_t*)(ws);
    ushort_t* Call  = (ushort_t*)(ws + (16u << 20));
    ushort_t* Wcat  = (ushort_t*)(ws + (80u << 20));
    ushort_t* GWCt  = (ushort_t*)(ws + (84u << 20));
    ushort_t* WPcat = (ushort_t*)(ws + (86u << 20));

    prep_kernel<<<44064, 256, 0, stream>>>(P, C1, C2, C3, C4, GWP, OW, GWC,
                                           Pb, Call, Wcat, GWCt, out);
    gemmA<<<512, 512, 0, stream>>>(Pb, Wcat, WPcat);
    gemmB_fused<<<1024, 512, 0, stream>>>(Call, GWCt, WPcat, Gb, Ob, out);
}

// Round 5
// 341.348 us; speedup vs baseline: 1.2327x; 1.1664x over previous
//
#include <hip/hip_runtime.h>
#include <hip/hip_bf16.h>

// PointerNet: out[b][k] = sum_c C_k[b,c] * sigmoid(WP[b,c]+WC_k[b,c]+Gb[c]) * (WPo[b,c]+Ob[c])
//   GEMM A: WPcat = P @ [GateWeight_P | OutWeight]  (M=8192,N=2048,K=1024)
//   GEMM B: WC_k = C_k @ GateWeight_C fused with sigmoid/dot epilogue (atomicAdd out).
// R5: register-direct epilogue in gemmB. R4's LDS/two-phase epilogue kept acc[4][4]
//     (64 VGPRs) live past the 128-reg __launch_bounds__(512,4) cap -> compiler
//     spilled exactly 150KB/block (WRITE_SIZE 153MB). Now each lane folds its own
//     C-fragment into row partial sums (fp32 WC, no bf16 round-trip), shfl_xor
//     reduction within the 16-lane quad group, 4 atomicAdds per mi from l16==0.
//     LDS back to 24KB staging only.

#define B_  8192
#define PD_ 1024
#define CD_ 1024

typedef unsigned short ushort_t;
typedef __attribute__((ext_vector_type(8))) short    short8;
typedef __attribute__((ext_vector_type(8))) unsigned short ushort8;
typedef __attribute__((ext_vector_type(4))) float    floatx4;

__device__ __forceinline__ float bf2f(unsigned short u) {
    return __uint_as_float(((unsigned)u) << 16);
}
__device__ __forceinline__ unsigned short f2bf(float f) {
    unsigned u = __float_as_uint(f);
    unsigned r = u + 0x7FFFu + ((u >> 16) & 1u);   // RNE
    return (unsigned short)(r >> 16);
}

// ---------------- prep: cast P,C1..C4 -> bf16; transpose 3 weights; zero out ----------------
__global__ __launch_bounds__(256) void prep_kernel(const float* __restrict__ P,
                                                   const float* __restrict__ C1,
                                                   const float* __restrict__ C2,
                                                   const float* __restrict__ C3,
                                                   const float* __restrict__ C4,
                                                   const float* __restrict__ GWP,
                                                   const float* __restrict__ OW,
                                                   const float* __restrict__ GWC,
                                                   ushort_t* __restrict__ Pb,
                                                   ushort_t* __restrict__ Call,
                                                   ushort_t* __restrict__ Wcat,
                                                   ushort_t* __restrict__ GWCt,
                                                   float* __restrict__ out) {
    const int bid = blockIdx.x;
    const int tid = threadIdx.x;
    if (bid < 40960) {
        const int seg = bid >> 13;
        const int i   = (bid & 8191) * 256 + tid;
        const float* src;
        ushort_t* dst;
        switch (seg) {
            case 0: src = P;  dst = Pb; break;
            case 1: src = C1; dst = Call; break;
            case 2: src = C2; dst = Call + (size_t)1 * B_ * CD_; break;
            case 3: src = C3; dst = Call + (size_t)2 * B_ * CD_; break;
            default: src = C4; dst = Call + (size_t)3 * B_ * CD_; break;
        }
        float4 v = ((const float4*)src)[i];
        ushort4 o;
        o.x = f2bf(v.x); o.y = f2bf(v.y); o.z = f2bf(v.z); o.w = f2bf(v.w);
        ((ushort4*)dst)[i] = o;
    } else if (bid < 44032) {
        __shared__ float tile[32][33];
        const int tb  = bid - 40960;
        const int seg = tb >> 10;
        const int t32 = tb & 1023;
        const float* src;
        ushort_t* dst;
        switch (seg) {
            case 0: src = GWP; dst = Wcat; break;
            case 1: src = OW;  dst = Wcat + 1024 * 1024; break;
            default: src = GWC; dst = GWCt; break;
        }
        const int c0 = (t32 & 31) * 32, r0 = (t32 >> 5) * 32;
        const int x = tid & 31, y = tid >> 5;
        for (int i = y; i < 32; i += 8)
            tile[i][x] = src[(size_t)(r0 + i) * 1024 + c0 + x];
        __syncthreads();
        for (int i = y; i < 32; i += 8)
            dst[(size_t)(c0 + i) * 1024 + r0 + x] = f2bf(tile[x][i]);
    } else {
        const int i = (bid - 44032) * 256 + tid;
        ((float4*)out)[i] = float4{0.f, 0.f, 0.f, 0.f};
    }
}

__device__ __forceinline__ void gl_lds16(const void* g, void* l) {
    __builtin_amdgcn_global_load_lds((const __attribute__((address_space(1))) void*)g,
                                     (__attribute__((address_space(3))) void*)l, 16, 0, 0);
}

// ---------------- GEMM A: WPcat = Pb @ Wcat^T  (128x256 tile, 512 thr) ----------------
// grid 512: xcd=bid&7, q=bid>>3; slab=(q>>3)*8+xcd (64 slabs), colt=q&7 (8 cols).
__global__ __launch_bounds__(512, 4) void gemmA(const ushort_t* __restrict__ A,
                                                const ushort_t* __restrict__ Bt,
                                                ushort_t* __restrict__ C) {
    __shared__ ushort_t smem[12288];      // lA 4096 + lB 8192 elems = 24 KB
    ushort_t* lA = smem;
    ushort_t* lB = smem + 4096;
    const int K = 1024, N = 2048;
    const int xcd = blockIdx.x & 7, q = blockIdx.x >> 3;
    const int tileM = ((q >> 3) * 8 + xcd) * 128;
    const int tileN = (q & 7) * 256;

    const int t = threadIdx.x;
    const int wave = t >> 6, lane = t & 63;
    const int quad = lane >> 4, l16 = lane & 15;
    const int wm = wave >> 2, wn = wave & 3;

    const int srow = lane >> 2;
    const int sc   = ((lane & 3) ^ ((lane >> 4) & 3)) * 8;
    const ushort_t* Ag  = A  + (size_t)(tileM + wave * 16 + srow) * K + sc;
    const ushort_t* Bg0 = Bt + (size_t)(tileN + wave * 32 + srow) * K + sc;
    const ushort_t* Bg1 = Bg0 + (size_t)16 * K;
    const int loA = wave * 512 + lane * 8;
    const int loB = wave * 1024 + lane * 8;
    const int fro = (l16 * 4 + (quad ^ (l16 >> 2))) * 8;

    floatx4 acc[4][4];
#pragma unroll
    for (int i = 0; i < 4; i++)
#pragma unroll
        for (int j = 0; j < 4; j++) acc[i][j] = (floatx4)0.f;

    for (int k0 = 0; k0 < K; k0 += 32) {
        gl_lds16(Ag + k0,  &lA[loA]);
        gl_lds16(Bg0 + k0, &lB[loB]);
        gl_lds16(Bg1 + k0, &lB[loB + 512]);
        __syncthreads();
        short8 af[4], bfr[4];
#pragma unroll
        for (int mi = 0; mi < 4; mi++)
            af[mi] = *(const short8*)&lA[(wm * 4 + mi) * 512 + fro];
#pragma unroll
        for (int ni = 0; ni < 4; ni++)
            bfr[ni] = *(const short8*)&lB[(wn * 4 + ni) * 512 + fro];
#pragma unroll
        for (int mi = 0; mi < 4; mi++)
#pragma unroll
            for (int ni = 0; ni < 4; ni++)
                acc[mi][ni] = __builtin_amdgcn_mfma_f32_16x16x32_bf16(
                    af[mi], bfr[ni], acc[mi][ni], 0, 0, 0);
        __syncthreads();
    }
#pragma unroll
    for (int mi = 0; mi < 4; mi++)
#pragma unroll
        for (int ni = 0; ni < 4; ni++)
#pragma unroll
            for (int r = 0; r < 4; r++) {
                int row = tileM + wm * 64 + mi * 16 + quad * 4 + r;
                int col = tileN + wn * 64 + ni * 16 + l16;
                C[(size_t)row * N + col] = f2bf(acc[mi][ni][r]);
            }
}

// ---------------- GEMM B + register-direct fused epilogue (128x256 tile, 512 thr) ----------------
// grid 1024: xcd=bid&7, q=bid>>3; slab=(q>>2)*8+xcd (256 slabs), colt=q&3 (4 cols).
// Lane owns C-fragment rows wm*64+mi*16+quad*4+r, col wn*64+ni*16+l16; it folds
// sigmoid/dot contributions straight out of acc (fp32), reduces across the 16-lane
// quad group, and l16==0 atomicAdds. acc never spills, WC never hits memory.
__global__ __launch_bounds__(512, 4) void gemmB_fused(const ushort_t* __restrict__ Call,
                                                      const ushort_t* __restrict__ GWCt,
                                                      const ushort_t* __restrict__ WPcat,
                                                      const float* __restrict__ Gb,
                                                      const float* __restrict__ Ob,
                                                      float* __restrict__ out) {
    __shared__ ushort_t smem[12288];      // 24 KB staging only
    ushort_t* lA = smem;
    ushort_t* lB = smem + 4096;
    const int K = 1024;
    const int xcd = blockIdx.x & 7, q = blockIdx.x >> 3;
    const int tileM = ((q >> 2) * 8 + xcd) * 128;
    const int tileN = (q & 3) * 256;

    const int t = threadIdx.x;
    const int wave = t >> 6, lane = t & 63;
    const int quad = lane >> 4, l16 = lane & 15;
    const int wm = wave >> 2, wn = wave & 3;

    const int srow = lane >> 2;
    const int sc   = ((lane & 3) ^ ((lane >> 4) & 3)) * 8;
    const ushort_t* Ag  = Call + (size_t)(tileM + wave * 16 + srow) * K + sc;
    const ushort_t* Bg0 = GWCt + (size_t)(tileN + wave * 32 + srow) * K + sc;
    const ushort_t* Bg1 = Bg0 + (size_t)16 * K;
    const int loA = wave * 512 + lane * 8;
    const int loB = wave * 1024 + lane * 8;
    const int fro = (l16 * 4 + (quad ^ (l16 >> 2))) * 8;

    floatx4 acc[4][4];
#pragma unroll
    for (int i = 0; i < 4; i++)
#pragma unroll
        for (int j = 0; j < 4; j++) acc[i][j] = (floatx4)0.f;

    for (int k0 = 0; k0 < K; k0 += 32) {
        gl_lds16(Ag + k0,  &lA[loA]);
        gl_lds16(Bg0 + k0, &lB[loB]);
        gl_lds16(Bg1 + k0, &lB[loB + 512]);
        __syncthreads();
        short8 af[4], bfr[4];
#pragma unroll
        for (int mi = 0; mi < 4; mi++)
            af[mi] = *(const short8*)&lA[(wm * 4 + mi) * 512 + fro];
#pragma unroll
        for (int ni = 0; ni < 4; ni++)
            bfr[ni] = *(const short8*)&lB[(wn * 4 + ni) * 512 + fro];
#pragma unroll
        for (int mi = 0; mi < 4; mi++)
#pragma unroll
            for (int ni = 0; ni < 4; ni++)
                acc[mi][ni] = __builtin_amdgcn_mfma_f32_16x16x32_bf16(
                    af[mi], bfr[ni], acc[mi][ni], 0, 0, 0);
        __syncthreads();
    }

    // ---- register-direct epilogue ----
    const int kk   = tileM >> 13;                        // choice index k (uniform per block)
    const int b0   = (tileM & 8191) + wm * 64 + quad * 4;  // batch row base (+mi*16+r)
    const int rowg = tileM + wm * 64 + quad * 4;           // grow base (+mi*16+r)

#pragma unroll
    for (int mi = 0; mi < 4; mi++) {
        float part[4] = {0.f, 0.f, 0.f, 0.f};
#pragma unroll
        for (int ni = 0; ni < 4; ni++) {
            const int gcol = tileN + wn * 64 + ni * 16 + l16;
            const float gbv = Gb[gcol];
            const float obv = Ob[gcol];
            const ushort_t* wpp = WPcat + (size_t)(b0 + mi * 16) * 2048 + gcol;
            const ushort_t* ckp = Call  + (size_t)(rowg + mi * 16) * 1024 + gcol;
#pragma unroll
            for (int r = 0; r < 4; r++) {
                float wp  = bf2f(wpp[(size_t)r * 2048]);
                float wpo = bf2f(wpp[(size_t)r * 2048 + 1024]);
                float ck  = bf2f(ckp[(size_t)r * 1024]);
                float x = wp + acc[mi][ni][r] + gbv;     // WC stays fp32
                float g = 1.f / (1.f + __expf(-x));
                part[r] += ck * g * (wpo + obv);
            }
        }
#pragma unroll
        for (int r = 0; r < 4; r++) {                    // reduce across 16-lane quad group
            part[r] += __shfl_xor(part[r], 1);
            part[r] += __shfl_xor(part[r], 2);
            part[r] += __shfl_xor(part[r], 4);
            part[r] += __shfl_xor(part[r], 8);
        }
        if (l16 == 0) {
#pragma unroll
            for (int r = 0; r < 4; r++)
                atomicAdd(&out[(size_t)(b0 + mi * 16 + r) * 4 + kk], part[r]);
        }
    }
}

extern "C" void kernel_launch(void* const* d_in, const int* in_sizes, int n_in,
                              void* d_out, int out_size, void* d_ws, size_t ws_size,
                              hipStream_t stream) {
    (void)in_sizes; (void)n_in; (void)out_size; (void)ws_size;
    const float* P   = (const float*)d_in[0];
    const float* C1  = (const float*)d_in[1];
    const float* C2  = (const float*)d_in[2];
    const float* C3  = (const float*)d_in[3];
    const float* C4  = (const float*)d_in[4];
    const float* GWP = (const float*)d_in[5];
    const float* GWC = (const float*)d_in[6];
    const float* Gb  = (const float*)d_in[7];
    const float* OW  = (const float*)d_in[8];
    const float* Ob  = (const float*)d_in[9];
    float* out = (float*)d_out;

    // workspace (bf16): Pb 16MiB | Call 64MiB | Wcat 4MiB | GWCt 2MiB | WPcat 32MiB
    char* ws = (char*)d_ws;
    ushort_t* Pb    = (ushort_t*)(ws);
    ushort_t* Call  = (ushort_t*)(ws + (16u << 20));
    ushort_t* Wcat  = (ushort_t*)(ws + (80u << 20));
    ushort_t* GWCt  = (ushort_t*)(ws + (84u << 20));
    ushort_t* WPcat = (ushort_t*)(ws + (86u << 20));

    prep_kernel<<<44064, 256, 0, stream>>>(P, C1, C2, C3, C4, GWP, OW, GWC,
                                           Pb, Call, Wcat, GWCt, out);
    gemmA<<<512, 512, 0, stream>>>(Pb, Wcat, WPcat);
    gemmB_fused<<<1024, 512, 0, stream>>>(Call, GWCt, WPcat, Gb, Ob, out);
}